// Round 8
// baseline (382.973 us; speedup 1.0000x reference)
//
#include <hip/hip_runtime.h>
#include <hip/hip_bf16.h>

constexpr int NN = 50000;
constexpr int EE = 200000;
typedef __bf16 bf16x8 __attribute__((ext_vector_type(8)));
typedef float f32x4 __attribute__((ext_vector_type(4)));

__device__ __forceinline__ float b2f(unsigned short s) {
    union { unsigned u; float f; } c; c.u = ((unsigned)s) << 16; return c.f;
}
__device__ __forceinline__ unsigned short f2b(float f) {
    union { float f; unsigned u; } c; c.f = f;
    unsigned u = c.u + 0x7fffu + ((c.u >> 16) & 1u);
    return (unsigned short)(u >> 16);
}
__device__ __forceinline__ float xv(const void* p, long i, int f32m) {
    return f32m ? ((const float*)p)[i] : b2f(((const unsigned short*)p)[i]);
}
__device__ __forceinline__ int iv(const int* p, int i, int i64m) {
    return i64m ? p[2 * i] : p[i];
}

// parallel dtype sniff: 256 threads, benign-race shared flags
__global__ void k_detect(const unsigned short* x16, const int* c32, int* flg) {
    __shared__ int sf, si;
    int t = threadIdx.x;
    if (t == 0) { sf = 0; si = 1; }
    __syncthreads();
    for (int i = t; i < 16384; i += 256)
        if (((x16[i] >> 7) & 0xFF) == 0xFF) sf = 1;
    if (t < 64)
        if (c32[2 * t + 1] != 0) si = 0;
    __syncthreads();
    if (t == 0) { flg[0] = sf; flg[1] = si; }
}

__global__ void k_zero(unsigned* p, int n) {
    int i = blockIdx.x * 256 + threadIdx.x;
    if (i < n) p[i] = 0u;
}

// x -> bf16 image xb (all structural gathers read this; half the bytes of f32)
__global__ void k_cast(const void* x, unsigned short* xb, const int* flg) {
    int i = blockIdx.x * 256 + threadIdx.x;       // 8 elements per thread
    if (i >= NN * 16) return;
    if (flg[0]) {
        const float4* xp = (const float4*)x + (size_t)i * 2;
        float4 u = xp[0], v = xp[1];
        unsigned short o[8] = { f2b(u.x), f2b(u.y), f2b(u.z), f2b(u.w),
                                f2b(v.x), f2b(v.y), f2b(v.z), f2b(v.w) };
        *(uint4*)(xb + (size_t)i * 8) = *(const uint4*)o;
    } else {
        ((uint4*)xb)[i] = ((const uint4*)x)[i];
    }
}

// Pack W into bf16 MFMA B-fragment image: chunk=(t*4+c)*64+l ;
// Wf[chunk*8+j] = W[c*32+(l>>4)*8+j][t*16+(l&15)]
__global__ void k_wfrag(const void* W, unsigned short* Wf, const int* flg) {
    int f32m = flg[0];
    int chunk = blockIdx.x * 256 + threadIdx.x;
    if (chunk >= 2048) return;
    int l = chunk & 63, c = (chunk >> 6) & 3, t = chunk >> 8;
    int n = t * 16 + (l & 15), k0 = c * 32 + ((l >> 4) * 8);
    for (int j = 0; j < 8; j++) Wf[chunk * 8 + j] = f2b(xv(W, (long)(k0 + j) * 128 + n, f32m));
}

// ---- CSR build (by col1), done once ----
__global__ void k_hist(const int* col1, int* counts, const int* flg) {
    int e = blockIdx.x * 256 + threadIdx.x;
    if (e >= EE) return;
    atomicAdd(&counts[iv(col1, e, flg[1])], 1);
}

// multi-block scan, stage 1: per-block sums (256 counts/block)
__global__ void k_scan1(const int* counts, int* bsum) {
    __shared__ int sh[256];
    int b = blockIdx.x, t = threadIdx.x;
    int idx = b * 256 + t;
    sh[t] = (idx < NN) ? counts[idx] : 0;
    __syncthreads();
    for (int off = 128; off > 0; off >>= 1) {
        if (t < off) sh[t] += sh[t + off];
        __syncthreads();
    }
    if (t == 0) bsum[b] = sh[0];
}

// stage 2: base = sum(bsum[0..b)), intra-block exclusive scan -> row_ptr/cursor
__global__ void k_scan2(const int* counts, const int* bsum,
                        int* row_ptr, int* cursor) {
    __shared__ int sh[256];
    __shared__ int base_s;
    int b = blockIdx.x, t = threadIdx.x;
    sh[t] = (t < b) ? bsum[t] : 0;
    __syncthreads();
    for (int off = 128; off > 0; off >>= 1) {
        if (t < off) sh[t] += sh[t + off];
        __syncthreads();
    }
    if (t == 0) base_s = sh[0];
    __syncthreads();
    int idx = b * 256 + t;
    int v = (idx < NN) ? counts[idx] : 0;
    sh[t] = v;
    __syncthreads();
    for (int off = 1; off < 256; off <<= 1) {
        int add = (t >= off) ? sh[t - off] : 0;
        __syncthreads();
        sh[t] += add;
        __syncthreads();
    }
    int ex = base_s + sh[t] - v;   // exclusive prefix
    if (idx < NN) { row_ptr[idx] = ex; cursor[idx] = ex; }
    if (idx == NN - 1) row_ptr[NN] = ex + v;
}

// position p (CSR slot under col1): aux[p] = col0[e] | selfloop<<31; node1[p] = col1[e].
// lgX is stored PERMUTED: edge e's features live at row p.
__global__ void k_cscatter(const int* col0, const int* col1, int* cursor,
                           unsigned* aux, int* node1, const int* flg) {
    int e = blockIdx.x * 256 + threadIdx.x;
    if (e >= EE) return;
    int i64m = flg[1];
    int a = iv(col0, e, i64m), b = iv(col1, e, i64m);
    int pos = atomicAdd(&cursor[b], 1);
    aux[pos] = (unsigned)a | (a == b ? 0x80000000u : 0u);
    node1[pos] = b;
}

// S[n][k] (bf16) = sum over non-self-loop in-edges of relu(msg).
//   mode 1: msg = 0.5*xb[col0] + 1.5*xb[n]   (bf16 gather, 256B rows)
//   mode 2: msg = lgX[p] + xb[n]             (SEQUENTIAL rows lo..hi)
// One wave per node; lane owns columns 2l,2l+1.
__global__ void k_gath(const unsigned short* xb, const unsigned short* lgX,
                       const int* row_ptr, const unsigned* aux,
                       unsigned short* S, int mode) {
    int n = blockIdx.x * 4 + (threadIdx.x >> 6);
    if (n >= NN) return;
    int l = threadIdx.x & 63, k0 = l * 2;
    int lo = row_ptr[n], hi = row_ptr[n + 1];
    unsigned un = *(const unsigned*)(xb + (size_t)n * 128 + k0);
    float xn0 = b2f((unsigned short)un), xn1 = b2f((unsigned short)(un >> 16));
    float a0 = 0.0f, a1 = 0.0f;
    if (mode == 1) {
        for (int p = lo; p < hi; p++) {
            unsigned av = aux[p];
            if (av & 0x80000000u) continue;
            unsigned u = *(const unsigned*)(xb + (size_t)av * 128 + k0);
            a0 += fmaxf(0.5f * b2f((unsigned short)u) + 1.5f * xn0, 0.0f);
            a1 += fmaxf(0.5f * b2f((unsigned short)(u >> 16)) + 1.5f * xn1, 0.0f);
        }
    } else {
        for (int p = lo; p < hi; p++) {
            if (aux[p] & 0x80000000u) continue;
            unsigned u = *(const unsigned*)(lgX + (size_t)p * 128 + k0);   // sequential
            a0 += fmaxf(b2f((unsigned short)u) + xn0, 0.0f);
            a1 += fmaxf(b2f((unsigned short)(u >> 16)) + xn1, 0.0f);
        }
    }
    unsigned o = ((unsigned)f2b(a1) << 16) | (unsigned)f2b(a0);
    *(unsigned*)(S + (size_t)n * 128 + k0) = o;
}

// Fused 2-layer MLP, BARRIER-FREE: each wave owns 16 CSR positions end-to-end.
// Out = (relu((A + S[col0]) @ W1 + b1)) @ W2 + b2, in-place on permuted lgX.
// Wave-private 4KB LDS region; all LDS deps same-wave (lgkmcnt only).
__global__ __launch_bounds__(256, 8)
void k_fused(const unsigned short* A, const unsigned short* S,
             const unsigned* aux, const int* node1, const unsigned short* xb,
             const void* bias1, const void* bias2,
             const unsigned short* Wf1, const unsigned short* Wf2,
             unsigned short* Out, const int* flg, int initA) {
    __shared__ unsigned short Lds[8192];   // 16 KB: 4 waves x 4 KB
    int f32m = flg[0];
    int tid = threadIdx.x;
    int w = tid >> 6, l = tid & 63;
    int lq = l >> 4, ln = l & 15;
    int e0 = blockIdx.x * 64 + w * 16;     // wave's 16 positions (EE % 64 == 0)
    unsigned short* W_ = Lds + w * 2048;   // wave-private region

    // ---- stage A-frag: lane l handles position e0+ln, k-group lq*8, c=0..3
    int row = e0 + ln;
    int aN = (int)(aux[row] & 0x7fffffffu);
    int bN = initA ? node1[row] : 0;
    for (int c = 0; c < 4; c++) {
        int k0 = c * 32 + lq * 8;
        uint4 svv = *(const uint4*)(S + (size_t)aN * 128 + k0);
        const unsigned short* sp = (const unsigned short*)&svv;
        unsigned short v[8];
        if (initA) {
            uint4 xav = *(const uint4*)(xb + (size_t)aN * 128 + k0);
            uint4 xbv = *(const uint4*)(xb + (size_t)bN * 128 + k0);
            const unsigned short* xa = (const unsigned short*)&xav;
            const unsigned short* xc = (const unsigned short*)&xbv;
            for (int j = 0; j < 8; j++)
                v[j] = f2b(0.5f * (b2f(xa[j]) + b2f(xc[j])) + b2f(sp[j]));
        } else {
            uint4 av = *(const uint4*)(A + (size_t)row * 128 + k0);
            const unsigned short* ap = (const unsigned short*)&av;
            for (int j = 0; j < 8; j++) v[j] = f2b(b2f(ap[j]) + b2f(sp[j]));
        }
        *(uint4*)(W_ + (c * 64 + l) * 8) = *(const uint4*)v;
    }

    // ---- GEMM1: rows 16, cols 128
    f32x4 acc[8];
    for (int j = 0; j < 8; j++)
        for (int r = 0; r < 4; r++) acc[j][r] = 0.0f;
    for (int c = 0; c < 4; c++) {
        bf16x8 af = *(const bf16x8*)(W_ + (c * 64 + l) * 8);
        for (int j = 0; j < 8; j++) {
            bf16x8 bf = *(const bf16x8*)(Wf1 + (size_t)(((j * 4 + c) * 64 + l) * 8));
            acc[j] = __builtin_amdgcn_mfma_f32_16x16x32_bf16(af, bf, acc[j], 0, 0, 0);
        }
    }

    // ---- H = relu(C1+b1) -> same region, A-frag order (same-wave dep only)
    for (int j = 0; j < 8; j++) {
        int n = j * 16 + ln;
        float bv = xv(bias1, n, f32m);
        int c2 = n >> 5, lhi = ((n >> 3) & 3) * 16, j2 = n & 7;
        for (int rg = 0; rg < 4; rg++) {
            float h = acc[j][rg] + bv;
            if (h < 0.0f) h = 0.0f;
            W_[(c2 * 64 + lhi + lq * 4 + rg) * 8 + j2] = f2b(h);
        }
    }

    // ---- GEMM2
    for (int j = 0; j < 8; j++)
        for (int r = 0; r < 4; r++) acc[j][r] = 0.0f;
    for (int c = 0; c < 4; c++) {
        bf16x8 af = *(const bf16x8*)(W_ + (c * 64 + l) * 8);
        for (int j = 0; j < 8; j++) {
            bf16x8 bf = *(const bf16x8*)(Wf2 + (size_t)(((j * 4 + c) * 64 + l) * 8));
            acc[j] = __builtin_amdgcn_mfma_f32_16x16x32_bf16(af, bf, acc[j], 0, 0, 0);
        }
    }

    // ---- C2 + b2 -> row-major in region, then coalesced uint4 store
    for (int j = 0; j < 8; j++) {
        int n = j * 16 + ln;
        float bv = xv(bias2, n, f32m);
        for (int rg = 0; rg < 4; rg++)
            W_[(lq * 4 + rg) * 128 + n] = f2b(acc[j][rg] + bv);
    }
    for (int i = 0; i < 4; i++) {
        int idx = i * 64 + l;    // 256 uint4 = 16 rows x 256B
        ((uint4*)Out)[(size_t)e0 * 16 + idx] = ((const uint4*)W_)[idx];
    }
}

// out[n] = x[n] + relu(mean over ALL in-edges of lgX rows lo..hi) (0 if deg==0).
// Fully sequential reads; residual uses original-precision x.
__global__ void LGNNGINELayer_12463995093126_kernel(
    const void* x, const unsigned short* lgX, const int* row_ptr,
    void* out, const int* flg) {
    int n = blockIdx.x * 4 + (threadIdx.x >> 6);
    if (n >= NN) return;
    int l = threadIdx.x & 63, k0 = l * 2;
    int f32m = flg[0];
    int lo = row_ptr[n], hi = row_ptr[n + 1];
    float a0 = 0.0f, a1 = 0.0f;
    for (int p = lo; p < hi; p++) {
        unsigned u = *(const unsigned*)(lgX + (size_t)p * 128 + k0);
        a0 += b2f((unsigned short)u);
        a1 += b2f((unsigned short)(u >> 16));
    }
    float g0 = 0.0f, g1 = 0.0f;
    if (hi > lo) {
        float inv = 1.0f / (float)(hi - lo);
        g0 = fmaxf(a0 * inv, 0.0f);
        g1 = fmaxf(a1 * inv, 0.0f);
    }
    if (f32m) {
        ((float*)out)[(long)n * 128 + k0]     = ((const float*)x)[(long)n * 128 + k0] + g0;
        ((float*)out)[(long)n * 128 + k0 + 1] = ((const float*)x)[(long)n * 128 + k0 + 1] + g1;
    } else {
        unsigned u = *(const unsigned*)((const unsigned short*)x + (long)n * 128 + k0);
        float r0 = b2f((unsigned short)u) + g0;
        float r1 = b2f((unsigned short)(u >> 16)) + g1;
        unsigned o = ((unsigned)f2b(r1) << 16) | (unsigned)f2b(r0);
        *(unsigned*)((unsigned short*)out + (long)n * 128 + k0) = o;
    }
}

extern "C" void kernel_launch(void* const* d_in, const int* in_sizes, int n_in,
                              void* d_out, int out_size, void* d_ws, size_t ws_size,
                              hipStream_t stream) {
    (void)in_sizes; (void)n_in; (void)out_size; (void)ws_size;
    const void* x = d_in[0];
    const void* W1 = d_in[1];
    const void* b1 = d_in[2];
    const void* W2 = d_in[3];
    const void* b2 = d_in[4];
    const int* col0 = (const int*)d_in[5];
    const int* col1 = (const int*)d_in[6];

    // ws: lgX(csr) | S | xb | row_ptr | cursor | counts | bsum | aux | node1 | flg | Wf1 | Wf2
    char* p = (char*)d_ws;
    unsigned short* lgX = (unsigned short*)p; p += (size_t)EE * 128 * 2;
    unsigned short* S = (unsigned short*)p;   p += (size_t)NN * 128 * 2;
    unsigned short* xb = (unsigned short*)p;  p += (size_t)NN * 128 * 2;
    int* row_ptr = (int*)p;                   p += (size_t)(NN + 16) * 4;
    int* cursor = (int*)p;                    p += (size_t)NN * 4;
    int* counts = (int*)p;                    p += (size_t)NN * 4;
    int* bsum = (int*)p;                      p += 256 * 4;
    unsigned* aux = (unsigned*)p;             p += (size_t)EE * 4;
    int* node1 = (int*)p;                     p += (size_t)EE * 4;
    int* flg = (int*)p;                       p += 256;
    unsigned short* Wf1 = (unsigned short*)p; p += 16384 * 2;
    unsigned short* Wf2 = (unsigned short*)p;

    int gB = EE / 64;                  // 3125 blocks, wave = 16 positions
    int eB = (EE + 255) / 256;
    int nB4 = (NN + 3) / 4;
    int sB = (NN + 255) / 256;         // 196 scan blocks
    int cB = (NN * 16 + 255) / 256;    // cast blocks

    k_detect<<<1, 256, 0, stream>>>((const unsigned short*)x, col0, flg);
    k_cast<<<cB, 256, 0, stream>>>(x, xb, flg);
    k_wfrag<<<8, 256, 0, stream>>>(W1, Wf1, flg);
    k_wfrag<<<8, 256, 0, stream>>>(W2, Wf2, flg);

    // CSR by col1 (col1 fixed across iterations)
    k_zero<<<(NN + 255) / 256, 256, 0, stream>>>((unsigned*)counts, NN);
    k_hist<<<eB, 256, 0, stream>>>(col1, counts, flg);
    k_scan1<<<sB, 256, 0, stream>>>(counts, bsum);
    k_scan2<<<sB, 256, 0, stream>>>(counts, bsum, row_ptr, cursor);
    k_cscatter<<<eB, 256, 0, stream>>>(col0, col1, cursor, aux, node1, flg);

    // iteration 1: S from xb directly, fused MLP -> lgX (CSR-permuted)
    k_gath<<<nB4, 256, 0, stream>>>(xb, lgX, row_ptr, aux, S, 1);
    k_fused<<<gB, 256, 0, stream>>>(lgX, S, aux, node1, xb, b1, b2,
                                    Wf1, Wf2, lgX, flg, 1);
    // iteration 2 (lgX reads sequential in k_gath)
    k_gath<<<nB4, 256, 0, stream>>>(xb, lgX, row_ptr, aux, S, 2);
    k_fused<<<gB, 256, 0, stream>>>(lgX, S, aux, node1, xb, b1, b2,
                                    Wf1, Wf2, lgX, flg, 0);
    // scatter_mean back to nodes (sequential CSR read) + residual/relu
    LGNNGINELayer_12463995093126_kernel<<<nB4, 256, 0, stream>>>(
        x, lgX, row_ptr, d_out, flg);
}